// Round 1
// baseline (467.265 us; speedup 1.0000x reference)
//
#include <hip/hip_runtime.h>
#include <hip/hip_bf16.h>

// Problem constants (from reference)
#define SCREEN_W 1280
#define SCREEN_H 720
#define TILE_L   16
#define NBW      80    // ceil(1280/16)
#define NBH      45    // ceil(720/16)
#define NUM_TILE 3600  // 80*45
#define N_POINTS 32768

typedef int v4i __attribute__((ext_vector_type(4)));

// ---------------------------------------------------------------------------
// Kernel A (unchanged, verified absmax 0): per-point tile-index ranges packed
// into one u32: ximin | ximax<<8 | yimin<<16 | yimax<<24 (half-open ranges).
// overlap_x(tile xi) <=> (xmin>>4) <= xi < ((xmax+15)>>4)
// Table: 32768 * 4 B = 128 KB in d_ws.
// ---------------------------------------------------------------------------
__global__ void aabb_kernel(const float* __restrict__ pos2d,
                            const float* __restrict__ radius,
                            unsigned int* __restrict__ pk) {
    int t = blockIdx.x * blockDim.x + threadIdx.x;   // thread handles 4 points
    int n = t * 4;
    if (n >= N_POINTS) return;

    const float4* p4 = (const float4*)(pos2d + 2 * n);
    float4 p01 = p4[0];   // x0 y0 x1 y1
    float4 p23 = p4[1];   // x2 y2 x3 y3
    float4 r   = *(const float4*)(radius + n);

    float xs[4] = {p01.x, p01.z, p23.x, p23.z};
    float ys[4] = {p01.y, p01.w, p23.y, p23.w};
    float rs[4] = {r.x, r.y, r.z, r.w};

    uint4 outp;
    unsigned int* op = &outp.x;
#pragma unroll
    for (int j = 0; j < 4; ++j) {
        float x = xs[j], y = ys[j], rr = rs[j];
        int xmin = (int)fminf(fmaxf(x - rr, 0.0f), (float)SCREEN_W);
        int ymin = (int)fminf(fmaxf(y - rr, 0.0f), (float)SCREEN_H);
        int xmax = (int)fminf(fmaxf(x + rr, 0.0f), (float)SCREEN_W);
        int ymax = (int)fminf(fmaxf(y + rr, 0.0f), (float)SCREEN_H);
        unsigned int ximin = (unsigned int)(xmin >> 4);          // <= 80
        unsigned int ximax = (unsigned int)((xmax + 15) >> 4);   // <= 80
        unsigned int yimin = (unsigned int)(ymin >> 4);          // <= 45
        unsigned int yimax = (unsigned int)((ymax + 15) >> 4);   // <= 45
        op[j] = ximin | (ximax << 8) | (yimin << 16) | (yimax << 24);
    }
    *(uint4*)(pk + n) = outp;
}

// ---------------------------------------------------------------------------
// Kernel B (R5: grid-stride restructure):
// R4's dim3(32,3600) = 115,200 blocks did ONE 16 B store per thread ->
// block launch/dispatch overhead dominated (3.3 TB/s vs 6.28 TB/s that the
// harness fill achieves on the same buffer). Now: dim3(2,3600) = 7,200
// blocks; each thread loops 16 uint4s (#pragma unroll 4 for ILP), so each
// wave amortizes launch cost over 16 KB of stores. Tile coords hoisted
// (computed once per thread, wave-uniform -> SALU).
// Output layout: out[t * N_POINTS + n]  (tile-major [T, N]).
// ---------------------------------------------------------------------------
__global__ void __launch_bounds__(256)
mask_kernel(const uint4* __restrict__ pk, int* __restrict__ out) {
    const int tile = blockIdx.y;
    const int half = blockIdx.x;     // 0 or 1: which half of the 32768 points

    const unsigned int xi = (unsigned int)(tile / NBH);
    const unsigned int yi = (unsigned int)(tile - (int)xi * NBH);

    // 32768 points / 4 per uint4 = 8192 uint4s; half = 4096; /256 thr = 16 iters
    const int ITERS = N_POINTS / 4 / 2 / 256;        // 16
    const int t0 = half * (N_POINTS / 4 / 2) + (int)threadIdx.x;
    int* __restrict__ outt = out + (size_t)tile * N_POINTS;

#pragma unroll 4
    for (int k = 0; k < ITERS; ++k) {
        const int t = t0 + k * 256;                  // uint4 index
        uint4 p = pk[t];
        const unsigned int* pp = &p.x;

        v4i res;
#pragma unroll
        for (int j = 0; j < 4; ++j) {
            unsigned int w = pp[j];
            unsigned int ximin =  w        & 0xFFu;
            unsigned int ximax = (w >> 8)  & 0xFFu;
            unsigned int yimin = (w >> 16) & 0xFFu;
            unsigned int yimax =  w >> 24;
            res[j] = (xi >= ximin && xi < ximax && yi >= yimin && yi < yimax) ? 1 : 0;
        }

        // PLAIN store (A/B'd vs __builtin_nontemporal_store in a previous
        // session; plain won — the harness fill reaches 6.35 TB/s with plain)
        *(v4i*)(outt + 4 * t) = res;
    }
}

extern "C" void kernel_launch(void* const* d_in, const int* in_sizes, int n_in,
                              void* d_out, int out_size, void* d_ws, size_t ws_size,
                              hipStream_t stream) {
    const float* pos2d  = (const float*)d_in[0];
    const float* radius = (const float*)d_in[1];
    int* out = (int*)d_out;
    unsigned int* pk = (unsigned int*)d_ws;   // 32768 * 4 B = 128 KB

    // Kernel A: 32768 points / 4 per thread = 8192 threads
    aabb_kernel<<<dim3(8192 / 256), dim3(256), 0, stream>>>(pos2d, radius, pk);

    // Kernel B: 2 half-chunks x 3600 tiles = 7,200 blocks, 16 uint4s/thread
    mask_kernel<<<dim3(2, NUM_TILE), dim3(256), 0, stream>>>((const uint4*)pk, out);
}